// Round 8
// baseline (170.984 us; speedup 1.0000x reference)
//
#include <hip/hip_runtime.h>
#include <hip/hip_bf16.h>
#include <cstddef>

// ---------------- problem constants ----------------
#define B_      4096
#define V_      778
#define J_      16
#define NB_     10
#define NC_     45
#define NROWS   2334      // V*3
#define PM_     135       // 9*(J-1)
#define KPW     192       // padded K for MFMA: 10 + 135 + 47 zeros = 6*32
#define NBTR    2496      // BT rows: 13*192 (vertex-aligned tiles)
#define LDK     104       // LDS k-stride (bf16): 96 + 8 pad

typedef __attribute__((ext_vector_type(8))) short short8v;
typedef __attribute__((ext_vector_type(4))) float f32x4;

// ---------------- workspace layout (float offsets) ----------------
#define WS_JS   0                                  // 480
#define WS_JT   480                                // 48
#define WS_ROT  1024                               // B*144
#define WS_J    (WS_ROT + (size_t)B_*144)          // B*48
#define WS_A2   (WS_J   + (size_t)B_*48)           // B*192
#define WS_ACT  (WS_A2  + (size_t)B_*192)          // B*192 bf16 = B*96 floats
#define WS_BT   (WS_ACT + (size_t)B_*96)           // NBTR*192 bf16
// total ~2.2M floats = 8.8 MB

// =====================================================================
// Kernel 1: batch-independent hoist (fp32, feeds joint regression)
// =====================================================================
__global__ __launch_bounds__(256) void k_js(const float* __restrict__ jreg,
                                            const float* __restrict__ shd,
                                            const float* __restrict__ tmpl,
                                            float* __restrict__ ws)
{
    int wid  = (blockIdx.x * 256 + threadIdx.x) >> 6;   // 528 waves
    int lane = threadIdx.x & 63;
    if (wid >= 528) return;
    float s = 0.f;
    if (wid < 480) {
        int i = wid / 30, rem = wid % 30, d = rem / 10, k = rem % 10;
        const float* jr = jreg + i * V_;
        for (int v = lane; v < V_; v += 64) s += jr[v] * shd[v*30 + d*10 + k];
    } else {
        int e = wid - 480, i = e / 3, d = e % 3;
        const float* jr = jreg + i * V_;
        for (int v = lane; v < V_; v += 64) s += jr[v] * tmpl[v*3 + d];
    }
    #pragma unroll
    for (int off = 32; off; off >>= 1) s += __shfl_down(s, off, 64);
    if (lane == 0) ws[wid] = s;
}

// =====================================================================
// Kernel 1b: BT_g[n][k] bf16, n-major k-contig. Block = one n row.
// =====================================================================
__global__ __launch_bounds__(256) void k_bt(const float* __restrict__ shd,
                                            const float* __restrict__ pdr,
                                            __hip_bfloat16* __restrict__ BTg)
{
    int n = blockIdx.x;                 // 0..NBTR-1
    int k = threadIdx.x;
    if (k >= KPW) return;
    float v = 0.f;
    if (n < NROWS) {
        if (k < NB_)            v = shd[n * NB_ + k];
        else if (k < NB_ + PM_) v = pdr[(size_t)n * PM_ + (k - NB_)];
    }
    BTg[(size_t)n * KPW + k] = __float2bfloat16(v);
}

// =====================================================================
// Kernel 2a: per (b,joint): pose matvec, rodrigues, ACT_g row (bf16), joints
// =====================================================================
__global__ __launch_bounds__(256) void k_rod(const float* __restrict__ pc,
                                             const float* __restrict__ betas,
                                             const float* __restrict__ sc,
                                             const float* __restrict__ hm,
                                             float* __restrict__ ws,
                                             __hip_bfloat16* __restrict__ ACTg)
{
    __shared__ float scs[NC_*45 + 45];
    for (int i = threadIdx.x; i < NC_*45 + 45; i += 256)
        scs[i] = (i < NC_*45) ? sc[i] : hm[i - NC_*45];
    __syncthreads();

    int gid = blockIdx.x * 256 + threadIdx.x;   // B*16 threads exactly
    int b = gid >> 4, i = gid & 15;
    const float* pcb = pc + b * 48;
    __hip_bfloat16* act = ACTg + (size_t)b * KPW;

    float a0, a1, a2;
    if (i == 0) { a0 = pcb[0]; a1 = pcb[1]; a2 = pcb[2]; }
    else {
        int col = (i - 1) * 3;
        float s0 = scs[NC_*45 + col], s1 = scs[NC_*45 + col + 1], s2 = scs[NC_*45 + col + 2];
        for (int k = 0; k < NC_; ++k) {
            float p = pcb[3 + k];
            s0 += p * scs[k*45 + col];
            s1 += p * scs[k*45 + col + 1];
            s2 += p * scs[k*45 + col + 2];
        }
        a0 = s0; a1 = s1; a2 = s2;
    }
    // rodrigues — mirror reference numerics
    float e0 = a0 + 1e-8f, e1 = a1 + 1e-8f, e2 = a2 + 1e-8f;
    float angle = sqrtf(e0*e0 + e1*e1 + e2*e2);
    float inv  = 1.f / angle;
    float half = 0.5f * angle;
    float sh = sinf(half), ch = cosf(half);
    float w = ch, x = sh * a0 * inv, y = sh * a1 * inv, z = sh * a2 * inv;
    float qn = 1.f / sqrtf(w*w + x*x + y*y + z*z);
    w *= qn; x *= qn; y *= qn; z *= qn;
    float w2 = w*w, x2 = x*x, y2 = y*y, z2 = z*z;
    float wx = w*x, wy = w*y, wz = w*z, xy = x*y, xz = x*z, yz = y*z;
    float R[9] = { w2+x2-y2-z2, 2*xy-2*wz,   2*wy+2*xz,
                   2*wz+2*xy,   w2-x2+y2-z2, 2*yz-2*wx,
                   2*xz-2*wy,   2*wx+2*yz,   w2-x2-y2+z2 };

    float* rot = ws + WS_ROT + (size_t)b*144 + i*9;
    #pragma unroll
    for (int q = 0; q < 9; ++q) rot[q] = R[q];

    if (i == 0) {
        const float* bb = betas + b * NB_;
        #pragma unroll
        for (int k = 0; k < NB_; ++k) act[k] = __float2bfloat16(bb[k]);
        for (int k = NB_ + PM_; k < KPW; ++k) act[k] = __float2bfloat16(0.f);
    } else {
        #pragma unroll
        for (int q = 0; q < 9; ++q) {
            float pv = R[q] - ((q == 0 || q == 4 || q == 8) ? 1.f : 0.f);
            act[NB_ + (i-1)*9 + q] = __float2bfloat16(pv);
        }
    }
    // joints: j[b,i,d] = Jt[i,d] + JS[i,d,:] . betas[b,:]
    const float* bb = betas + b * NB_;
    float* jout = ws + WS_J + (size_t)b*48 + i*3;
    #pragma unroll
    for (int d = 0; d < 3; ++d) {
        const float* jsrow = ws + WS_JS + (i*3 + d) * NB_;
        float s = ws[WS_JT + i*3 + d];
        #pragma unroll
        for (int k = 0; k < NB_; ++k) s += jsrow[k] * bb[k];
        jout[d] = s;
    }
}

// =====================================================================
// Kernel 2b: kinematic chain, thread = (batch, finger, row-m). 61440 threads.
// =====================================================================
__global__ __launch_bounds__(256) void k_chain(const float* __restrict__ trans,
                                               float* __restrict__ ws,
                                               float* __restrict__ out_jtr)
{
    int gid = blockIdx.x * 256 + threadIdx.x;    // exactly B*15
    int b = gid / 15, rem = gid % 15, f = rem / 3, m = rem % 3;
    const float* rot = ws + WS_ROT + (size_t)b*144;
    const float* j   = ws + WS_J   + (size_t)b*48;
    float* a2 = ws + WS_A2 + (size_t)b*192;
    float* jt = out_jtr + (size_t)b*63;
    const int INV[16] = {0,5,6,7,9,10,11,17,18,19,13,14,15,1,2,3};
    float trm = trans[b*3 + m];

    float j0x = j[0], j0y = j[1], j0z = j[2];
    float T0 = rot[m*3+0], T1 = rot[m*3+1], T2 = rot[m*3+2];
    float T3 = (m == 0) ? j0x : (m == 1) ? j0y : j0z;
    if (f == 0) {
        float corr = T0*j0x + T1*j0y + T2*j0z;
        a2[m*4+0] = T0; a2[m*4+1] = T1; a2[m*4+2] = T2; a2[m*4+3] = T3 - corr;
        jt[m] = (T3 + trm) * 1000.f;
    }
    float jpx = j0x, jpy = j0y, jpz = j0z;
    for (int s = 0; s < 3; ++s) {
        int i = f*3 + 1 + s;
        const float* R = rot + i*9;
        float jix = j[i*3], jiy = j[i*3+1], jiz = j[i*3+2];
        float d0 = jix - jpx, d1 = jiy - jpy, d2 = jiz - jpz;
        float n0 = T0*R[0] + T1*R[3] + T2*R[6];
        float n1 = T0*R[1] + T1*R[4] + T2*R[7];
        float n2 = T0*R[2] + T1*R[5] + T2*R[8];
        float n3 = T0*d0 + T1*d1 + T2*d2 + T3;
        T0 = n0; T1 = n1; T2 = n2; T3 = n3;
        float corr = T0*jix + T1*jiy + T2*jiz;
        a2[i*12 + m*4 + 0] = T0; a2[i*12 + m*4 + 1] = T1;
        a2[i*12 + m*4 + 2] = T2; a2[i*12 + m*4 + 3] = T3 - corr;
        jt[INV[i]*3 + m] = (T3 + trm) * 1000.f;
        jpx = jix; jpy = jiy; jpz = jiz;
    }
}

// =====================================================================
// Kernel 3: FUSED MFMA GEMM + LBS blend. Tile 64 b x 192 n (64 vertices).
// 4 waves 2x2 (wave: 32 rows x 96 cols, acc[2][6]). vp tile -> LDS
// [64][196] fp32 (pad 196: 4-row write conflicts 2-way = free), weights
// transposed in LDS tail. Blend: thread = (row, vgroup16); A2 read from
// global (lane-merged same-address, L1-hot), 16 FMA per load.
// LDS 54,272 B -> 3 blocks/CU.
// =====================================================================
__global__ __launch_bounds__(256) void k_fuse(const __hip_bfloat16* __restrict__ ACTg,
                                              const __hip_bfloat16* __restrict__ BTg,
                                              const float* __restrict__ tmpl,
                                              const float* __restrict__ wts,
                                              const float* __restrict__ trans,
                                              const float* __restrict__ ws,
                                              float* __restrict__ out)
{
    __shared__ float smem[13568];               // 54,272 B
    ushort* lA  = (ushort*)smem;                // [64][LDK]
    ushort* lB  = lA + 64 * LDK;                // [192][LDK]
    float*  vps = smem;                         // [64][196] (epilogue)
    float*  wtt = smem + 64 * 196;              // [16][64]  (epilogue)

    const int tid  = threadIdx.x;
    const int lane = tid & 63;
    const int wid  = tid >> 6;
    const int wm   = wid >> 1;                  // 0..1 (row half)
    const int wn   = wid & 1;                   // 0..1 (col half)
    const int l15  = lane & 15;
    const int lhi  = lane >> 4;
    const int n0   = blockIdx.x * 192;
    const int v0   = blockIdx.x * 64;
    const int b0   = blockIdx.y * 64;

    f32x4 acc[2][6] = {};

    for (int kc = 0; kc < KPW; kc += 96) {
        #pragma unroll
        for (int it = 0; it < 3; ++it) {        // A: 64 rows x 12 chunks
            int idx = it * 256 + tid;
            int row = idx / 12, ch = idx % 12;
            *(uint4*)&lA[row*LDK + ch*8] =
                *(const uint4*)(ACTg + (size_t)(b0 + row) * KPW + kc + ch*8);
        }
        #pragma unroll
        for (int it = 0; it < 9; ++it) {        // B: 192 rows x 12 chunks
            int idx = it * 256 + tid;
            int row = idx / 12, ch = idx % 12;
            *(uint4*)&lB[row*LDK + ch*8] =
                *(const uint4*)(BTg + (size_t)(n0 + row) * KPW + kc + ch*8);
        }
        __syncthreads();
        #pragma unroll
        for (int ks = 0; ks < 3; ++ks) {
            int kl = ks*32 + lhi*8;
            short8v a[2], bv[6];
            #pragma unroll
            for (int mt = 0; mt < 2; ++mt)
                a[mt] = *(const short8v*)&lA[(wm*32 + mt*16 + l15)*LDK + kl];
            #pragma unroll
            for (int nt = 0; nt < 6; ++nt)
                bv[nt] = *(const short8v*)&lB[(wn*96 + nt*16 + l15)*LDK + kl];
            #pragma unroll
            for (int mt = 0; mt < 2; ++mt)
                #pragma unroll
                for (int nt = 0; nt < 6; ++nt)
                    acc[mt][nt] = __builtin_amdgcn_mfma_f32_16x16x32_bf16(
                        a[mt], bv[nt], acc[mt][nt], 0, 0, 0);
        }
        __syncthreads();
    }

    // ---- acc (+tmpl) -> vps LDS tile ----
    #pragma unroll
    for (int nt = 0; nt < 6; ++nt) {
        int coll = wn*96 + nt*16 + l15;
        int colg = n0 + coll;
        float tv = (colg < NROWS) ? tmpl[colg] : 0.f;
        #pragma unroll
        for (int mt = 0; mt < 2; ++mt) {
            int rowl = wm*32 + mt*16 + lhi*4;
            #pragma unroll
            for (int r = 0; r < 4; ++r)
                vps[(rowl + r)*196 + coll] = acc[mt][nt][r] + tv;
        }
    }
    // ---- weights transposed into LDS tail ----
    {
        int vv = tid >> 2, q = tid & 3;
        int gv = v0 + vv;
        float4 wv = (gv < V_) ? *(const float4*)(wts + gv*16 + q*4)
                              : make_float4(0.f, 0.f, 0.f, 0.f);
        wtt[(q*4+0)*64 + vv] = wv.x;
        wtt[(q*4+1)*64 + vv] = wv.y;
        wtt[(q*4+2)*64 + vv] = wv.z;
        wtt[(q*4+3)*64 + vv] = wv.w;
    }
    __syncthreads();

    // ---- blend: thread = (row, vgroup of 16), 4 chunks of 4 vertices ----
    const int row = tid >> 2;
    const int vg  = tid & 3;
    const int b   = b0 + row;
    const float* a2r = ws + WS_A2 + (size_t)b * 192;
    float t0 = trans[b*3], t1 = trans[b*3+1], t2 = trans[b*3+2];
    const int TIPS[5] = {745, 317, 444, 556, 673};
    const int TIPK[5] = {4, 8, 12, 16, 20};

    #pragma unroll
    for (int c = 0; c < 4; ++c) {
        int vbase = vg*16 + c*4;
        float T[4][12] = {};
        #pragma unroll
        for (int jj = 0; jj < 16; ++jj) {
            float4 x0 = *(const float4*)&a2r[jj*12];
            float4 x1 = *(const float4*)&a2r[jj*12 + 4];
            float4 x2 = *(const float4*)&a2r[jj*12 + 8];
            #pragma unroll
            for (int vv = 0; vv < 4; ++vv) {
                float wj = wtt[jj*64 + vbase + vv];
                T[vv][0] += wj*x0.x; T[vv][1] += wj*x0.y; T[vv][2]  += wj*x0.z; T[vv][3]  += wj*x0.w;
                T[vv][4] += wj*x1.x; T[vv][5] += wj*x1.y; T[vv][6]  += wj*x1.z; T[vv][7]  += wj*x1.w;
                T[vv][8] += wj*x2.x; T[vv][9] += wj*x2.y; T[vv][10] += wj*x2.z; T[vv][11] += wj*x2.w;
            }
        }
        #pragma unroll
        for (int vv = 0; vv < 4; ++vv) {
            int vl = vbase + vv;
            int v  = v0 + vl;
            float p0 = vps[row*196 + vl*3];
            float p1 = vps[row*196 + vl*3 + 1];
            float p2 = vps[row*196 + vl*3 + 2];
            float o0 = T[vv][0]*p0 + T[vv][1]*p1 + T[vv][2]*p2  + T[vv][3];
            float o1 = T[vv][4]*p0 + T[vv][5]*p1 + T[vv][6]*p2  + T[vv][7];
            float o2 = T[vv][8]*p0 + T[vv][9]*p1 + T[vv][10]*p2 + T[vv][11];
            float r0 = (o0 + t0)*1000.f, r1 = (o1 + t1)*1000.f, r2 = (o2 + t2)*1000.f;
            if (v < V_) {
                float* vo = out + (size_t)b*NROWS + v*3;
                vo[0] = r0; vo[1] = r1; vo[2] = r2;
                #pragma unroll
                for (int t = 0; t < 5; ++t) {
                    if (v == TIPS[t]) {
                        float* jt = out + (size_t)B_*NROWS + (size_t)b*63 + TIPK[t]*3;
                        jt[0] = r0; jt[1] = r1; jt[2] = r2;
                    }
                }
            }
        }
    }
}

// =====================================================================
extern "C" void kernel_launch(void* const* d_in, const int* in_sizes, int n_in,
                              void* d_out, int out_size, void* d_ws, size_t ws_size,
                              hipStream_t stream)
{
    const float* pc    = (const float*)d_in[0];  // (B,48)
    const float* betas = (const float*)d_in[1];  // (B,10)
    const float* trans = (const float*)d_in[2];  // (B,3)
    const float* shd   = (const float*)d_in[3];  // (2334,10)
    const float* pdr   = (const float*)d_in[4];  // (2334,135)
    const float* tmpl  = (const float*)d_in[5];  // (2334)
    const float* jreg  = (const float*)d_in[6];  // (16,V)
    const float* wts   = (const float*)d_in[7];  // (V,16)
    const float* sc    = (const float*)d_in[8];  // (45,45)
    const float* hm    = (const float*)d_in[9];  // (45)
    float* out = (float*)d_out;
    float* ws  = (float*)d_ws;   // needs ~8.8 MB

    __hip_bfloat16* ACTg = (__hip_bfloat16*)(ws + WS_ACT);
    __hip_bfloat16* BTg  = (__hip_bfloat16*)(ws + WS_BT);

    hipLaunchKernelGGL(k_js,    dim3(132),       dim3(256), 0, stream, jreg, shd, tmpl, ws);
    hipLaunchKernelGGL(k_bt,    dim3(NBTR),      dim3(256), 0, stream, shd, pdr, BTg);
    hipLaunchKernelGGL(k_rod,   dim3(B_*16/256), dim3(256), 0, stream, pc, betas, sc, hm, ws, ACTg);
    hipLaunchKernelGGL(k_chain, dim3(B_*15/256), dim3(256), 0, stream, trans, ws,
                       out + (size_t)B_ * NROWS);
    hipLaunchKernelGGL(k_fuse,  dim3(13, 64),    dim3(256), 0, stream,
                       ACTg, BTg, tmpl, wts, trans, ws, out);
}

// Round 9
// 144.410 us; speedup vs baseline: 1.1840x; 1.1840x over previous
//
#include <hip/hip_runtime.h>
#include <hip/hip_bf16.h>
#include <cstddef>

// ---------------- problem constants ----------------
#define B_      4096
#define V_      778
#define J_      16
#define NB_     10
#define NC_     45
#define NROWS   2334      // V*3
#define PM_     135       // 9*(J-1)
#define KPW     192       // padded K for MFMA: 10 + 135 + 47 zeros = 6*32
#define NPW     2432      // padded N: 19*128
#define LDK     104       // LDS k-stride (bf16): 96 + 8 pad

typedef __attribute__((ext_vector_type(8))) short short8v;
typedef __attribute__((ext_vector_type(4))) float f32x4;

// ---------------- workspace layout (float offsets) ----------------
#define WS_JS   0                                  // 480
#define WS_JT   480                                // 48
#define WS_A2   1024                               // B*192
#define WS_VP   (WS_A2  + (size_t)B_*192)          // B*NPW fp32
#define WS_ACT  (WS_VP  + (size_t)B_*NPW)          // B*192 bf16 = B*96 floats
#define WS_BT   (WS_ACT + (size_t)B_*96)           // NPW*192 bf16
// total ~11.4M floats = 45.5 MB

// =====================================================================
// Kernel 1: k_prep = BT pack (blocks 0..NPW-1)  +  JS/JT hoist (last 132).
// =====================================================================
__global__ __launch_bounds__(256) void k_prep(const float* __restrict__ jreg,
                                              const float* __restrict__ shd,
                                              const float* __restrict__ pdr,
                                              const float* __restrict__ tmpl,
                                              float* __restrict__ ws,
                                              __hip_bfloat16* __restrict__ BTg)
{
    int bx = blockIdx.x;
    if (bx < NPW) {                       // ---- BT row pack ----
        int n = bx, k = threadIdx.x;
        if (k >= KPW) return;
        float v = 0.f;
        if (n < NROWS) {
            if (k < NB_)            v = shd[n * NB_ + k];
            else if (k < NB_ + PM_) v = pdr[(size_t)n * PM_ + (k - NB_)];
        }
        BTg[(size_t)n * KPW + k] = __float2bfloat16(v);
        return;
    }
    // ---- JS / JT hoist: 528 waves over 132 blocks ----
    int wid  = ((bx - NPW) * 256 + threadIdx.x) >> 6;
    int lane = threadIdx.x & 63;
    if (wid >= 528) return;
    float s = 0.f;
    if (wid < 480) {
        int i = wid / 30, rem = wid % 30, d = rem / 10, k = rem % 10;
        const float* jr = jreg + i * V_;
        for (int v = lane; v < V_; v += 64) s += jr[v] * shd[v*30 + d*10 + k];
    } else {
        int e = wid - 480, i = e / 3, d = e % 3;
        const float* jr = jreg + i * V_;
        for (int v = lane; v < V_; v += 64) s += jr[v] * tmpl[v*3 + d];
    }
    #pragma unroll
    for (int off = 32; off; off >>= 1) s += __shfl_down(s, off, 64);
    if (lane == 0) ws[wid] = s;
}

// =====================================================================
// Kernel 2: k_pose = rodrigues (+ACT +joints) then kinematic chain.
// Block = 16 batches x 16 joints = 256 threads. R and j live in LDS only.
// Phase B: 240 threads = (local batch, finger, row-m).
// =====================================================================
__global__ __launch_bounds__(256) void k_pose(const float* __restrict__ pc,
                                              const float* __restrict__ betas,
                                              const float* __restrict__ sc,
                                              const float* __restrict__ hm,
                                              const float* __restrict__ trans,
                                              float* __restrict__ ws,
                                              __hip_bfloat16* __restrict__ ACTg,
                                              float* __restrict__ out_jtr)
{
    __shared__ float scs[NC_*45 + 45];    // 8.3 KB
    __shared__ float sR[16 * 144];        // 9.2 KB
    __shared__ float sj[16 * 48];         // 3.0 KB
    const int tid = threadIdx.x;
    for (int i = tid; i < NC_*45 + 45; i += 256)
        scs[i] = (i < NC_*45) ? sc[i] : hm[i - NC_*45];
    __syncthreads();

    // ---- phase A: per (b, joint) ----
    {
        int bl = tid >> 4, i = tid & 15;
        int b  = blockIdx.x * 16 + bl;
        const float* pcb = pc + b * 48;
        __hip_bfloat16* act = ACTg + (size_t)b * KPW;

        float a0, a1, a2;
        if (i == 0) { a0 = pcb[0]; a1 = pcb[1]; a2 = pcb[2]; }
        else {
            int col = (i - 1) * 3;
            float s0 = scs[NC_*45 + col], s1 = scs[NC_*45 + col + 1], s2 = scs[NC_*45 + col + 2];
            for (int k = 0; k < NC_; ++k) {
                float p = pcb[3 + k];
                s0 += p * scs[k*45 + col];
                s1 += p * scs[k*45 + col + 1];
                s2 += p * scs[k*45 + col + 2];
            }
            a0 = s0; a1 = s1; a2 = s2;
        }
        // rodrigues — mirror reference numerics
        float e0 = a0 + 1e-8f, e1 = a1 + 1e-8f, e2 = a2 + 1e-8f;
        float angle = sqrtf(e0*e0 + e1*e1 + e2*e2);
        float inv  = 1.f / angle;
        float half = 0.5f * angle;
        float sh = sinf(half), ch = cosf(half);
        float w = ch, x = sh * a0 * inv, y = sh * a1 * inv, z = sh * a2 * inv;
        float qn = 1.f / sqrtf(w*w + x*x + y*y + z*z);
        w *= qn; x *= qn; y *= qn; z *= qn;
        float w2 = w*w, x2 = x*x, y2 = y*y, z2 = z*z;
        float wx = w*x, wy = w*y, wz = w*z, xy = x*y, xz = x*z, yz = y*z;
        float R[9] = { w2+x2-y2-z2, 2*xy-2*wz,   2*wy+2*xz,
                       2*wz+2*xy,   w2-x2+y2-z2, 2*yz-2*wx,
                       2*xz-2*wy,   2*wx+2*yz,   w2-x2-y2+z2 };
        #pragma unroll
        for (int q = 0; q < 9; ++q) sR[bl*144 + i*9 + q] = R[q];

        if (i == 0) {
            const float* bb = betas + b * NB_;
            #pragma unroll
            for (int k = 0; k < NB_; ++k) act[k] = __float2bfloat16(bb[k]);
            for (int k = NB_ + PM_; k < KPW; ++k) act[k] = __float2bfloat16(0.f);
        } else {
            #pragma unroll
            for (int q = 0; q < 9; ++q) {
                float pv = R[q] - ((q == 0 || q == 4 || q == 8) ? 1.f : 0.f);
                act[NB_ + (i-1)*9 + q] = __float2bfloat16(pv);
            }
        }
        // joints
        const float* bb = betas + b * NB_;
        #pragma unroll
        for (int d = 0; d < 3; ++d) {
            const float* jsrow = ws + WS_JS + (i*3 + d) * NB_;
            float s = ws[WS_JT + i*3 + d];
            #pragma unroll
            for (int k = 0; k < NB_; ++k) s += jsrow[k] * bb[k];
            sj[bl*48 + i*3 + d] = s;
        }
    }
    __syncthreads();

    // ---- phase B: chain, 240 threads ----
    if (tid >= 240) return;
    int bl = tid / 15, rem = tid % 15, f = rem / 3, m = rem % 3;
    int b  = blockIdx.x * 16 + bl;
    const float* rot = &sR[bl * 144];
    const float* j   = &sj[bl * 48];
    float* a2 = ws + WS_A2 + (size_t)b*192;
    float* jt = out_jtr + (size_t)b*63;
    const int INV[16] = {0,5,6,7,9,10,11,17,18,19,13,14,15,1,2,3};
    float trm = trans[b*3 + m];

    float j0x = j[0], j0y = j[1], j0z = j[2];
    float T0 = rot[m*3+0], T1 = rot[m*3+1], T2 = rot[m*3+2];
    float T3 = (m == 0) ? j0x : (m == 1) ? j0y : j0z;
    if (f == 0) {
        float corr = T0*j0x + T1*j0y + T2*j0z;
        a2[m*4+0] = T0; a2[m*4+1] = T1; a2[m*4+2] = T2; a2[m*4+3] = T3 - corr;
        jt[m] = (T3 + trm) * 1000.f;
    }
    float jpx = j0x, jpy = j0y, jpz = j0z;
    for (int s = 0; s < 3; ++s) {
        int i = f*3 + 1 + s;
        const float* R = rot + i*9;
        float jix = j[i*3], jiy = j[i*3+1], jiz = j[i*3+2];
        float d0 = jix - jpx, d1 = jiy - jpy, d2 = jiz - jpz;
        float n0 = T0*R[0] + T1*R[3] + T2*R[6];
        float n1 = T0*R[1] + T1*R[4] + T2*R[7];
        float n2 = T0*R[2] + T1*R[5] + T2*R[8];
        float n3 = T0*d0 + T1*d1 + T2*d2 + T3;
        T0 = n0; T1 = n1; T2 = n2; T3 = n3;
        float corr = T0*jix + T1*jiy + T2*jiz;
        a2[i*12 + m*4 + 0] = T0; a2[i*12 + m*4 + 1] = T1;
        a2[i*12 + m*4 + 2] = T2; a2[i*12 + m*4 + 3] = T3 - corr;
        jt[INV[i]*3 + m] = (T3 + trm) * 1000.f;
        jpx = jix; jpy = jiy; jpz = jiz;
    }
}

// =====================================================================
// Kernel 3: MFMA v_posed GEMM (unchanged from R7). vp = ACT·BT^T + tmpl.
// 128x128 tile, 4 waves 2x2, 16x16x32 bf16 MFMA, K in 2 chunks of 96.
// =====================================================================
__global__ __launch_bounds__(256) void k_mfma(const __hip_bfloat16* __restrict__ ACTg,
                                              const __hip_bfloat16* __restrict__ BTg,
                                              const float* __restrict__ tmpl,
                                              float* __restrict__ vp)
{
    __shared__ ushort lA[128 * LDK];
    __shared__ ushort lB[128 * LDK];

    const int tid  = threadIdx.x;
    const int lane = tid & 63;
    const int wid  = tid >> 6;
    const int wm   = wid >> 1;           // 0..1
    const int wn   = wid & 1;            // 0..1
    const int b0   = blockIdx.y * 128;
    const int n0   = blockIdx.x * 128;
    const int l15  = lane & 15;
    const int lhi  = lane >> 4;

    f32x4 acc[4][4] = {};

    for (int kc = 0; kc < KPW; kc += 96) {
        #pragma unroll
        for (int it = 0; it < 6; ++it) {
            int idx = it * 256 + tid;
            int row = idx / 12, ch = idx % 12;
            const uint4* sa = (const uint4*)(ACTg + (size_t)(b0 + row) * KPW + kc + ch*8);
            *(uint4*)&lA[row*LDK + ch*8] = *sa;
            const uint4* sb = (const uint4*)(BTg + (size_t)(n0 + row) * KPW + kc + ch*8);
            *(uint4*)&lB[row*LDK + ch*8] = *sb;
        }
        __syncthreads();
        #pragma unroll
        for (int ks = 0; ks < 3; ++ks) {
            int kl = ks*32 + lhi*8;
            short8v a[4], bf[4];
            #pragma unroll
            for (int mt = 0; mt < 4; ++mt)
                a[mt] = *(const short8v*)&lA[(wm*64 + mt*16 + l15)*LDK + kl];
            #pragma unroll
            for (int nt = 0; nt < 4; ++nt)
                bf[nt] = *(const short8v*)&lB[(wn*64 + nt*16 + l15)*LDK + kl];
            #pragma unroll
            for (int mt = 0; mt < 4; ++mt)
                #pragma unroll
                for (int nt = 0; nt < 4; ++nt)
                    acc[mt][nt] = __builtin_amdgcn_mfma_f32_16x16x32_bf16(
                        a[mt], bf[nt], acc[mt][nt], 0, 0, 0);
        }
        __syncthreads();
    }
    #pragma unroll
    for (int nt = 0; nt < 4; ++nt) {
        int col = n0 + wn*64 + nt*16 + l15;
        float tv = (col < NROWS) ? tmpl[col] : 0.f;
        #pragma unroll
        for (int mt = 0; mt < 4; ++mt) {
            int rbase = b0 + wm*64 + mt*16 + lhi*4;
            #pragma unroll
            for (int r = 0; r < 4; ++r)
                vp[(size_t)(rbase + r) * NPW + col] = acc[mt][nt][r] + tv;
        }
    }
}

// =====================================================================
// Kernel 4: LBS blend v3 (unchanged from R7). Block = 4 batches x 64 verts.
// =====================================================================
__global__ __launch_bounds__(256) void k_blend3(const float* __restrict__ wts,
                                                const float* __restrict__ trans,
                                                const float* __restrict__ ws,
                                                float* __restrict__ out)
{
    __shared__ float s_wt[16 * 64];     // [j][vl]
    __shared__ float s_a2[4 * 192];
    __shared__ float s_vp[4 * 192];
    const int tid = threadIdx.x;
    const int v0  = blockIdx.x * 64;
    const int b0  = blockIdx.y * 4;
    const int bl  = tid >> 6;
    const int vl  = tid & 63;
    const int b   = b0 + bl;
    const int v   = v0 + vl;

    {
        int vv = tid >> 2, q = tid & 3;
        int gv = v0 + vv;
        float4 wv = (gv < V_) ? *(const float4*)(wts + gv*16 + q*4)
                              : make_float4(0.f, 0.f, 0.f, 0.f);
        s_wt[(q*4+0)*64 + vv] = wv.x;
        s_wt[(q*4+1)*64 + vv] = wv.y;
        s_wt[(q*4+2)*64 + vv] = wv.z;
        s_wt[(q*4+3)*64 + vv] = wv.w;
    }
    if (tid < 192) {
        int bg = tid / 48, i = tid % 48;
        *(float4*)&s_a2[bg*192 + i*4] =
            *(const float4*)(ws + WS_A2 + (size_t)(b0 + bg)*192 + i*4);
        *(float4*)&s_vp[bg*192 + i*4] =
            *(const float4*)(ws + WS_VP + (size_t)(b0 + bg)*NPW + v0*3 + i*4);
    }
    __syncthreads();

    const float* a2r = &s_a2[bl * 192];
    float T[12] = {};
    #pragma unroll
    for (int jj = 0; jj < 16; ++jj) {
        float wj = s_wt[jj*64 + vl];
        float4 x0 = *(const float4*)&a2r[jj*12];
        float4 x1 = *(const float4*)&a2r[jj*12 + 4];
        float4 x2 = *(const float4*)&a2r[jj*12 + 8];
        T[0] += wj*x0.x; T[1] += wj*x0.y; T[2]  += wj*x0.z; T[3]  += wj*x0.w;
        T[4] += wj*x1.x; T[5] += wj*x1.y; T[6]  += wj*x1.z; T[7]  += wj*x1.w;
        T[8] += wj*x2.x; T[9] += wj*x2.y; T[10] += wj*x2.z; T[11] += wj*x2.w;
    }
    float p0 = s_vp[bl*192 + vl*3];
    float p1 = s_vp[bl*192 + vl*3 + 1];
    float p2 = s_vp[bl*192 + vl*3 + 2];
    float o0 = T[0]*p0 + T[1]*p1 + T[2]*p2  + T[3];
    float o1 = T[4]*p0 + T[5]*p1 + T[6]*p2  + T[7];
    float o2 = T[8]*p0 + T[9]*p1 + T[10]*p2 + T[11];

    float t0 = trans[b*3], t1 = trans[b*3+1], t2 = trans[b*3+2];
    float r0 = (o0 + t0)*1000.f, r1 = (o1 + t1)*1000.f, r2 = (o2 + t2)*1000.f;

    if (v < V_) {
        float* vo = out + (size_t)b*NROWS + v*3;
        vo[0] = r0; vo[1] = r1; vo[2] = r2;
        const int TIPS[5] = {745, 317, 444, 556, 673};
        const int TIPK[5] = {4, 8, 12, 16, 20};
        #pragma unroll
        for (int t = 0; t < 5; ++t) {
            if (v == TIPS[t]) {
                float* jt = out + (size_t)B_*NROWS + (size_t)b*63 + TIPK[t]*3;
                jt[0] = r0; jt[1] = r1; jt[2] = r2;
            }
        }
    }
}

// =====================================================================
extern "C" void kernel_launch(void* const* d_in, const int* in_sizes, int n_in,
                              void* d_out, int out_size, void* d_ws, size_t ws_size,
                              hipStream_t stream)
{
    const float* pc    = (const float*)d_in[0];  // (B,48)
    const float* betas = (const float*)d_in[1];  // (B,10)
    const float* trans = (const float*)d_in[2];  // (B,3)
    const float* shd   = (const float*)d_in[3];  // (2334,10)
    const float* pdr   = (const float*)d_in[4];  // (2334,135)
    const float* tmpl  = (const float*)d_in[5];  // (2334)
    const float* jreg  = (const float*)d_in[6];  // (16,V)
    const float* wts   = (const float*)d_in[7];  // (V,16)
    const float* sc    = (const float*)d_in[8];  // (45,45)
    const float* hm    = (const float*)d_in[9];  // (45)
    float* out = (float*)d_out;
    float* ws  = (float*)d_ws;   // needs ~45.5 MB

    __hip_bfloat16* ACTg = (__hip_bfloat16*)(ws + WS_ACT);
    __hip_bfloat16* BTg  = (__hip_bfloat16*)(ws + WS_BT);
    float* vp = ws + WS_VP;

    hipLaunchKernelGGL(k_prep,   dim3(NPW + 132), dim3(256), 0, stream,
                       jreg, shd, pdr, tmpl, ws, BTg);
    hipLaunchKernelGGL(k_pose,   dim3(B_/16),     dim3(256), 0, stream,
                       pc, betas, sc, hm, trans, ws, ACTg,
                       out + (size_t)B_ * NROWS);
    hipLaunchKernelGGL(k_mfma,   dim3(19, 32),    dim3(256), 0, stream, ACTg, BTg, tmpl, vp);
    hipLaunchKernelGGL(k_blend3, dim3(13, B_/4),  dim3(256), 0, stream, wts, trans, ws, out);
}